// Round 6
// baseline (30.175 us; speedup 1.0000x reference)
//
#include <hip/hip_runtime.h>

// Out: (4,64,64,64,32) fp32. In: (4,32,32,32,32) fp32. 2x trilinear upsample,
// TF1 legacy mapping: src = dst*0.5, frac in {0,0.5}, hi = min(lo+1,31).
//
// R6: write-linear restructure. One block = (b, od, j) owns the contiguous
// 64 KB output slab out[b, od, 8j..8j+7, :, :]. Staging computes the
// d-RESOLVED plane (D-lerp first, matching reference axis order) for the 5
// needed h-rows into 20 KB LDS; compute phase does H-lerp then W-lerp and
// stores fully linearly: each wave store = contiguous 1 KB, block walks its
// slab front-to-back. Tests the "scattered 8KB write chunks lose ~20% DRAM
// page locality vs fill's linear streams" theory.
typedef float floatx4 __attribute__((ext_vector_type(4)));

__global__ __launch_bounds__(256) void resize3d_lds(
    const floatx4* __restrict__ in, floatx4* __restrict__ out) {
    __shared__ floatx4 P[5 * 32 * 8];   // [h_i 0..4][w 0..31][c4 0..7], 20 KB

    const int t = threadIdx.x;
    const int bid = blockIdx.x;         // b(2) | od(6) | j(3)
    const int j  = bid & 7;
    const int od = (bid >> 3) & 63;
    const int b  = bid >> 9;

    const int dlo = od >> 1;
    const int dhi = min(dlo + 1, 31);
    const bool dmid = (od & 1) != 0;    // uniform per block

    // ---- stage: d-resolved rows h_g = min(4j+r, 31), full (w,C) ----
    const floatx4* inb = in + ((size_t)b << 18);
#pragma unroll
    for (int r = 0; r < 5; ++r) {
        const int hg = min(4 * j + r, 31);
        floatx4 v = inb[(dlo << 13) + (hg << 8) + t];   // 1 KB/wave, coalesced
        if (dmid) {
            floatx4 n = inb[(dhi << 13) + (hg << 8) + t];
            v = v + (n - v) * 0.5f;     // D-lerp (frac 0.5); even od: frac 0 = v
        }
        P[r * 256 + t] = v;
    }
    __syncthreads();

    // ---- compute: 16 outputs/thread, stores fully linear in t ----
    const int c4  = t & 7;
    const int wq  = t >> 4;             // w0 base within half
    const int fwp = (t >> 3) & 1;       // ow parity -> fw in {0, 0.5}
    floatx4* ob = out + ((size_t)b << 21) + (od << 15) + (j << 12);

#pragma unroll
    for (int kw = 0; kw < 2; ++kw) {    // low/high 32 of ow
        const int w0 = kw ? 16 + wq : wq;
        const int w1 = min(w0 + 1, 31);
#pragma unroll
        for (int m = 0; m < 8; ++m) {   // oh_i = m, oh = 8j + m
            const int h0 = m >> 1;      // local staged row; fh = m&1
            floatx4 a = P[(h0 * 32 + w0) * 8 + c4];
            floatx4 bb = P[(h0 * 32 + w1) * 8 + c4];
            if (m & 1) {                // H-lerp (frac 0.5); even m exact copy
                floatx4 a1 = P[((h0 + 1) * 32 + w0) * 8 + c4];
                floatx4 b1 = P[((h0 + 1) * 32 + w1) * 8 + c4];
                a  = a  + (a1 - a)  * 0.5f;
                bb = bb + (b1 - bb) * 0.5f;
            }
            // W-lerp: fw=0 lanes take a exactly
            floatx4 res = fwp ? (a + (bb - a) * 0.5f) : a;
            // out f4 index within slab: (m*2+kw)*256 + t  (linear per wave)
            __builtin_nontemporal_store(res, ob + (m * 2 + kw) * 256 + t);
        }
    }
}

extern "C" void kernel_launch(void* const* d_in, const int* in_sizes, int n_in,
                              void* d_out, int out_size, void* d_ws, size_t ws_size,
                              hipStream_t stream) {
    const floatx4* in = (const floatx4*)d_in[0];
    floatx4* out = (floatx4*)d_out;
    const int grid = 4 * 64 * 8;        // 2048 blocks, 64 KB linear slab each
    resize3d_lds<<<grid, 256, 0, stream>>>(in, out);
}

// Round 7
// 28.834 us; speedup vs baseline: 1.0465x; 1.0465x over previous
//
#include <hip/hip_runtime.h>

// Out: (4,64,64,64,32) fp32. In: (4,32,32,32,32) fp32. Pure 2x trilinear
// upsample, TF1 legacy mapping: src = dst*0.5, frac in {0,0.5}, hi=min(lo+1,31).
//
// FINAL (= R5, best measured 28.8 us). One thread owns (b, d-group of 2, h0,
// w0, c4); keeps the current input d-plane's 4 corners in registers, loads
// only the next plane per iteration (12 loads / 16 float4 outputs), writes
// the 2x2x2 blocks with non-temporal float4 stores. Grid = 2048 blocks =
// one full residency round.
//
// Tested and refuted for the residual vs the ~24 us copy-ceiling estimate:
//   - NT stores (R4: neutral), ILP/d-rolling (R5: -2%),
//   - write-linear 64KB slabs + LDS staging (R6: regression).
// Residual attributed to graph-replay launch overhead + mixed R/W DRAM
// turnaround (structural).
typedef float floatx4 __attribute__((ext_vector_type(4)));

__global__ __launch_bounds__(256) void resize3d_up2(
    const floatx4* __restrict__ in, floatx4* __restrict__ out) {
    const int tid = threadIdx.x;        // 256 = 32 w0 x 8 c4
    const int c4 = tid & 7;
    const int w0 = tid >> 3;            // 0..31
    const int bid = blockIdx.x;         // 0..2047 = b(2) | dg(4) | h0(5)
    const int h0 = bid & 31;
    const int dg = (bid >> 5) & 15;     // group of 2 d-planes
    const int b  = bid >> 9;            // 0..3

    const int h1 = min(h0 + 1, 31);
    const int w1 = min(w0 + 1, 31);
    const int d0 = dg << 1;

    // input float4 offset: (((b*32+d)*32+h)*32+w)*8 + c4
    const floatx4* inb = in + ((size_t)b << 18) + c4;
#define VIDX(d, h, w) (((d) << 13) + ((h) << 8) + ((w) << 3))
    floatx4 c00 = inb[VIDX(d0, h0, w0)];
    floatx4 c01 = inb[VIDX(d0, h0, w1)];
    floatx4 c10 = inb[VIDX(d0, h1, w0)];
    floatx4 c11 = inb[VIDX(d0, h1, w1)];

    // output float4 offset: (b<<21) + (od<<15) + (oh<<9) + (ow<<3) + c4,
    // oh = 2*h0, ow = 2*w0
    floatx4* outb0 = out + ((size_t)b << 21) + (h0 << 10) + (w0 << 4) + c4;

#define LERP4(a, b) ((a) + ((b) - (a)) * 0.5f)
#define NTST(p, v) __builtin_nontemporal_store((v), (p))
#define EMIT_PLANE(p00, p01, p10, p11, base)                \
    do {                                                    \
        floatx4 eh  = LERP4(p00, p10);       /* rh=1,rw=0 */\
        floatx4 eh2 = LERP4(p01, p11);                      \
        NTST((base) + 0,   p00);             /* rh=0,rw=0 */\
        NTST((base) + 8,   LERP4(p00, p01)); /* rh=0,rw=1 */\
        NTST((base) + 512, eh);                             \
        NTST((base) + 520, LERP4(eh, eh2));  /* rh=1,rw=1 */\
    } while (0)

#pragma unroll
    for (int it = 0; it < 2; ++it) {
        const int d  = d0 + it;
        const int dn = min(d + 1, 31);
        floatx4 n00 = inb[VIDX(dn, h0, w0)];
        floatx4 n01 = inb[VIDX(dn, h0, w1)];
        floatx4 n10 = inb[VIDX(dn, h1, w0)];
        floatx4 n11 = inb[VIDX(dn, h1, w1)];

        // D-midplane corners (od = 2d+1, frac 0.5)
        floatx4 q00 = LERP4(c00, n00);
        floatx4 q01 = LERP4(c01, n01);
        floatx4 q10 = LERP4(c10, n10);
        floatx4 q11 = LERP4(c11, n11);

        floatx4* ob = outb0 + ((size_t)d << 16);   // od = 2d plane
        EMIT_PLANE(c00, c01, c10, c11, ob);        // rd = 0
        EMIT_PLANE(q00, q01, q10, q11, ob + 32768);// rd = 1

        c00 = n00; c01 = n01; c10 = n10; c11 = n11;
    }
#undef EMIT_PLANE
#undef NTST
#undef LERP4
#undef VIDX
}

extern "C" void kernel_launch(void* const* d_in, const int* in_sizes, int n_in,
                              void* d_out, int out_size, void* d_ws, size_t ws_size,
                              hipStream_t stream) {
    const floatx4* in = (const floatx4*)d_in[0];
    floatx4* out = (floatx4*)d_out;
    // 16 float4 outputs per thread, 256 threads per block
    const int grid = out_size / (4 * 16 * 256);   // 2048 blocks, no tail
    resize3d_up2<<<grid, 256, 0, stream>>>(in, out);
}